// Round 5
// baseline (193.063 us; speedup 1.0000x reference)
//
#include <hip/hip_runtime.h>

typedef unsigned short u16;
typedef __attribute__((ext_vector_type(8))) __bf16 bf16x8;
typedef __attribute__((ext_vector_type(4))) float f32x4;
typedef __attribute__((ext_vector_type(4))) u16 u16x4;

// ---------------- helpers ----------------

__device__ __forceinline__ u16 f2bf(float f) {
  unsigned u = __float_as_uint(f);
  u += 0x7fff + ((u >> 16) & 1);   // RNE
  return (u16)(u >> 16);
}

__device__ __forceinline__ f32x4 mfma16(bf16x8 a, bf16x8 b, f32x4 c) {
  return __builtin_amdgcn_mfma_f32_16x16x32_bf16(a, b, c, 0, 0, 0);
}

__device__ __forceinline__ void gload16(const void* g, void* l) {
  __builtin_amdgcn_global_load_lds(
      (__attribute__((address_space(1))) unsigned int*)(const_cast<void*>(g)),
      (__attribute__((address_space(3))) unsigned int*)l, 16, 0, 0);
}

// ---------------- prep kernels (fused) ----------------

__global__ void k_f32_to_bf16(const float* __restrict__ in, u16* __restrict__ out, int n4) {
  int i = blockIdx.x * blockDim.x + threadIdx.x;
  if (i < n4) {
    float4 v = reinterpret_cast<const float4*>(in)[i];
    u16x4 o;
    o.x = f2bf(v.x); o.y = f2bf(v.y); o.z = f2bf(v.z); o.w = f2bf(v.w);
    reinterpret_cast<u16x4*>(out)[i] = o;
  }
}

// rel f32->bf16 (blocks 0..63) + bias pack (blocks 64..75) in one launch
__global__ void k_prep_small(const float* __restrict__ rel, u16* __restrict__ relb,
                             const float* __restrict__ bq, const float* __restrict__ bk,
                             const float* __restrict__ bv, float* __restrict__ bias) {
  const int bx = blockIdx.x, t = threadIdx.x;
  if (bx < 64) {
    int i = bx * 256 + t;          // 16384 float4 chunks
    float4 v = reinterpret_cast<const float4*>(rel)[i];
    u16x4 o;
    o.x = f2bf(v.x); o.y = f2bf(v.y); o.z = f2bf(v.z); o.w = f2bf(v.w);
    reinterpret_cast<u16x4*>(relb)[i] = o;
  } else {
    int i = (bx - 64) * 256 + t;
    if (i < 3072) bias[i] = (i < 1024) ? bq[i] : (i < 2048 ? bk[i - 1024] : bv[i - 2048]);
  }
}

// Wt[n][k] = W[k][n], fp32 -> bf16, all four weights in one launch (grid.z = 4)
__global__ void k_transpose_w4(const float* __restrict__ W0, const float* __restrict__ W1,
                               const float* __restrict__ W2, const float* __restrict__ W3,
                               u16* __restrict__ outbase) {
  __shared__ float tile[32][33];
  const int z = blockIdx.z;
  const float* in = (z == 0) ? W0 : (z == 1) ? W1 : (z == 2) ? W2 : W3;
  u16* out = outbase + (size_t)z * 1024 * 1024;
  const int r0 = blockIdx.y * 32, c0 = blockIdx.x * 32;
  const int t = threadIdx.x;
  for (int i = t; i < 1024; i += 256) {
    int r = i >> 5, c = i & 31;
    tile[r][c] = in[(size_t)(r0 + r) * 1024 + c0 + c];
  }
  __syncthreads();
  for (int i = t; i < 1024; i += 256) {
    int r = i >> 5, c = i & 31;
    out[(size_t)(c0 + r) * 1024 + r0 + c] = f2bf(tile[c][r]);
  }
}

// ---------------- GEMM: C[m][n] = sum_k A[m][k]*B[n][k] + bias[n] ----------------
// MODE 0: fp32 output. MODE 2: bf16 output, and cols >= 2048 (the V block of the
// fused QKV GEMM) are routed to Vaux in transposed layout
// Vaux[(b*1024 + (col-2048))*1024 + s], replacing the separate transpose kernel.

template<int MODE>
__global__ __launch_bounds__(256) void k_gemm(
    const u16* __restrict__ A, const u16* __restrict__ B,
    const float* __restrict__ bias, void* __restrict__ Cout,
    u16* __restrict__ Vaux, int M, int N, int Kd)
{
  __shared__ u16 Alds[128 * 32];
  __shared__ u16 Blds[128 * 32];
  const int t = threadIdx.x;
  const int lane = t & 63, wid = t >> 6;
  const int wr = wid >> 1, wc = wid & 1;
  const int l15 = lane & 15, lg = lane >> 4;
  const int m0 = blockIdx.y * 128, n0 = blockIdx.x * 128;
  const int trow = t >> 2;
  const int tcol = (t & 3) * 8;

  const f32x4 fzero = {0.f, 0.f, 0.f, 0.f};
  f32x4 acc[4][4];
#pragma unroll
  for (int i = 0; i < 4; i++)
#pragma unroll
    for (int j = 0; j < 4; j++) acc[i][j] = fzero;

  const size_t aoff0 = (size_t)(m0 + trow) * Kd + tcol;
  const size_t aoff1 = (size_t)(m0 + 64 + trow) * Kd + tcol;
  const size_t boff0 = (size_t)(n0 + trow) * Kd + tcol;
  const size_t boff1 = (size_t)(n0 + 64 + trow) * Kd + tcol;
  u16* la0 = Alds + wid * 512;
  u16* la1 = Alds + 2048 + wid * 512;
  u16* lb0 = Blds + wid * 512;
  u16* lb1 = Blds + 2048 + wid * 512;

  for (int k0 = 0; k0 < Kd; k0 += 32) {
    gload16(A + aoff0 + k0, la0);
    gload16(A + aoff1 + k0, la1);
    gload16(B + boff0 + k0, lb0);
    gload16(B + boff1 + k0, lb1);
    __syncthreads();
    bf16x8 av[4], bv[4];
#pragma unroll
    for (int mi = 0; mi < 4; mi++)
      av[mi] = *reinterpret_cast<const bf16x8*>(Alds + (wr * 64 + mi * 16 + l15) * 32 + lg * 8);
#pragma unroll
    for (int ni = 0; ni < 4; ni++)
      bv[ni] = *reinterpret_cast<const bf16x8*>(Blds + (wc * 64 + ni * 16 + l15) * 32 + lg * 8);
#pragma unroll
    for (int mi = 0; mi < 4; mi++)
#pragma unroll
      for (int ni = 0; ni < 4; ni++)
        acc[mi][ni] = mfma16(av[mi], bv[ni], acc[mi][ni]);
    __syncthreads();
  }

#pragma unroll
  for (int mi = 0; mi < 4; mi++) {
#pragma unroll
    for (int ni = 0; ni < 4; ni++) {
      const int col = n0 + wc * 64 + ni * 16 + l15;
      const float bcol = bias[col];
#pragma unroll
      for (int r = 0; r < 4; r++) {
        const int row = m0 + wr * 64 + mi * 16 + lg * 4 + r;
        const float v = acc[mi][ni][r] + bcol;
        if (MODE == 0) {
          ((float*)Cout)[(size_t)row * N + col] = v;
        } else {
          if (col < 2048) {
            ((u16*)Cout)[(size_t)row * N + col] = f2bf(v);
          } else {
            const int bb = row >> 10, ss = row & 1023;
            Vaux[((size_t)bb * 1024 + (col - 2048)) * 1024 + ss] = f2bf(v);
          }
        }
      }
    }
  }
}

// ---------------- attention ----------------
// v6: evidence from rounds 0-4 says this kernel is LATENCY-bound and scales
// with resident independent blocks (4 blk/CU ~64us; both 2 blk/CU pipelined
// variants 93-118us). So: keep the PROVEN round-3 iteration (single-buffered
// stage -> sync -> compute; rel loads inline, consumed immediately) and double
// the block-level TLP instead:
//   - 2 waves / 32 q-rows per block -> 2048 blocks of 128 threads;
//   - LDS cut to exactly 20480 B (K 8K + V 8K + P 4K) by replacing the W-band
//     LDS round-trip with the correctness-validated in-register shuffle
//     combine (rounds 1/4) -- NO hoisted rel register arrays (round-2 lesson);
//   - 8 blocks x 2 waves = 16 waves/CU resident (vs 8.3 time-avg before).
// K/V tiles are staged twice (once per 32-row block) -- cheap redundant issue
// traded for 2x outstanding-latency overlap; K/V/rel stay L2-resident per bh
// since co-resident blocks share bh (blk & 63).

__global__ __launch_bounds__(128, 4) void k_attn(
    const u16* __restrict__ qkv,   // (4096, 3072): Q|K|V
    const u16* __restrict__ vt,    // (64*64, 1024): Vt[bh*64+d][s]
    const u16* __restrict__ relb,  // (1024, 64)
    u16* __restrict__ Oout)        // (4096, 1024)
{
  __shared__ u16 Klds[64 * 64];      // 8 KB, swizzled: byte = row*128 + (cb ^ ((row&7)<<4))
  __shared__ u16 Vlds[64 * 64];      // 8 KB, same swizzle (rows = d)
  __shared__ u16 Plds[2][16 * 64];   // 4 KB, per-wave P (bf16), swizzled rows of 128B

  const int t = threadIdx.x;           // 0..127
  const int lane = t & 63, w = t >> 6; // w in {0,1}
  const int l15 = lane & 15, lg = lane >> 4;
  const int blk = blockIdx.x;
  const int bh = blk & 63;             // co-resident blocks share bh (L2/XCD locality)
  const int g = blk >> 6;              // 0..31
  const int j = 31 - g;                // heavy-first dispatch (LPT)
  const int b = bh >> 4, h = bh & 15;
  const int qb = j * 32;               // 32 q-rows per block
  const int qw = qb + w * 16;

  u16* Pb = Plds[w];
  const f32x4 fzero = {0.f, 0.f, 0.f, 0.f};

  // Q A-fragments, held in registers
  const size_t qrow = (size_t)(b * 1024 + qw + l15) * 3072 + h * 64;
  bf16x8 aQ0 = *reinterpret_cast<const bf16x8*>(qkv + qrow + lg * 8);
  bf16x8 aQ1 = *reinterpret_cast<const bf16x8*>(qkv + qrow + 32 + lg * 8);

  f32x4 oacc[4];
  float l_r[4];
#pragma unroll
  for (int r = 0; r < 4; r++) { oacc[r] = fzero; l_r[r] = 0.f; }

  // staging: 1024 16B chunks (K 512 + V 512); thread t stages K/V chunks
  // {t, t+128, t+256, t+384}. chunk c: row = c>>3 (= t>>3 + 16*ci, so row&7 --
  // and hence the swizzle -- is ci-invariant), col byte = (c&7)*16, source col
  // inverse-swizzled so LDS holds the swizzled layout with a linear dest.
  const int srow = t >> 3;             // 0..15
  const int scb = ((t & 7) * 16) ^ ((srow & 7) << 4);
  const u16* Ks0 = qkv + (size_t)(b * 1024 + srow) * 3072 + 1024 + h * 64 + (scb >> 1);
  const u16* Vs0 = vt + (size_t)(bh * 64 + srow) * 1024 + (scb >> 1);

  const int nk = (j >> 1) + 1;         // k-tiles needed by rows qb..qb+31
  const float SC = 0.125f * 1.44269504f;   // fold 1/sqrt(D) and log2(e)

  for (int kt = 0; kt < nk; kt++) {
    const int k0 = kt * 64;
#pragma unroll
    for (int ci = 0; ci < 4; ci++) {
      gload16(Ks0 + (size_t)(k0 + 16 * ci) * 3072, Klds + (t + 128 * ci) * 8);
      gload16(Vs0 + (size_t)(16384 * ci) + k0,     Vlds + (t + 128 * ci) * 8);
    }
    __syncthreads();   // drains vmcnt for both waves; K/V tile ready

    // content scores: 16 q x 64 k from swizzled Klds
    f32x4 sc4[4];
#pragma unroll
    for (int tt = 0; tt < 4; tt++) sc4[tt] = fzero;
#pragma unroll
    for (int tt = 0; tt < 4; tt++) {
      const int row = tt * 16 + l15;
      const int sw = (row & 7) << 4;
      bf16x8 b0 = *reinterpret_cast<const bf16x8*>((const char*)Klds + row * 128 + ((lg * 16) ^ sw));
      bf16x8 b1 = *reinterpret_cast<const bf16x8*>((const char*)Klds + row * 128 + ((64 + lg * 16) ^ sw));
      sc4[tt] = mfma16(aQ0, b0, sc4[tt]);
      sc4[tt] = mfma16(aQ1, b1, sc4[tt]);
    }

    // rel band: z[wj] rows = lg*4+r, cols = band pos wj*16 + l15.
    // loads inline, consumed immediately (short live ranges -- round-2 lesson).
    const int rbase = 1008 + k0 - qw;
    f32x4 z[5];
#pragma unroll
    for (int wj = 0; wj < 5; wj++) {
      int rr = rbase + wj * 16 + l15;
      rr = rr < 0 ? 0 : (rr > 1023 ? 1023 : rr);   // clamped rows feed only masked entries
      const u16* rp = relb + rr * 64;
      bf16x8 b0 = *reinterpret_cast<const bf16x8*>(rp + lg * 8);
      bf16x8 b1 = *reinterpret_cast<const bf16x8*>(rp + 32 + lg * 8);
      f32x4 zz = fzero;
      zz = mfma16(aQ0, b0, zz);
      zz = mfma16(aQ1, b1, zz);
      z[wj] = zz;
    }

    // combine + mask + exp2 (defer-max: static max 0) + P write.
    // band pos needed = tt*16 + u, u = l15+15-rowi; same row as producer ->
    // within-16-group rotation (validated rounds 1/4).
#pragma unroll
    for (int r = 0; r < 4; r++) {
      const int rowi = lg * 4 + r;
      const int q = qw + rowi;
      const int u = l15 + 15 - rowi;               // in [0,30]
      const int src = (lane & 48) | (u & 15);
      float sz[5];
#pragma unroll
      for (int wj = 0; wj < 5; wj++) sz[wj] = __shfl(z[wj][r], src);
#pragma unroll
      for (int tt = 0; tt < 4; tt++) {
        const int kg = k0 + tt * 16 + l15;
        const float wv = (u & 16) ? sz[tt + 1] : sz[tt];
        const float s = (sc4[tt][r] + wv) * SC;
        const float p = (kg <= q) ? exp2f(s) : 0.f;
        l_r[r] += p;
        const int cb = (32 * tt + 2 * l15) ^ ((rowi & 7) << 4);
        *(u16*)((char*)Pb + rowi * 128 + cb) = f2bf(p);
      }
    }
    __builtin_amdgcn_wave_barrier();
    asm volatile("" ::: "memory");     // order P writes before P reads

    // PV from swizzled Plds (A) and Vlds (B)
#pragma unroll
    for (int s = 0; s < 2; s++) {
      const int acb = (s * 64 + lg * 16) ^ ((l15 & 7) << 4);
      bf16x8 aP = *reinterpret_cast<const bf16x8*>((const char*)Pb + l15 * 128 + acb);
#pragma unroll
      for (int dt = 0; dt < 4; dt++) {
        const int vrow = dt * 16 + l15;
        const int vcb = (s * 64 + lg * 16) ^ ((vrow & 7) << 4);
        bf16x8 bV = *reinterpret_cast<const bf16x8*>((const char*)Vlds + vrow * 128 + vcb);
        oacc[dt] = mfma16(aP, bV, oacc[dt]);
      }
    }
    __syncthreads();   // both waves done with K/V before restaging
  }

  // epilogue: one row-sum reduce, scale, store
#pragma unroll
  for (int r = 0; r < 4; r++) {
    float l = l_r[r];
#pragma unroll
    for (int xm = 1; xm < 16; xm <<= 1) l += __shfl_xor(l, xm);
    const float inv = 1.f / l;
    const int q = qw + lg * 4 + r;
#pragma unroll
    for (int dt = 0; dt < 4; dt++)
      Oout[(size_t)(b * 1024 + q) * 1024 + h * 64 + dt * 16 + l15] = f2bf(oacc[dt][r] * inv);
  }
}

// ---------------- launcher ----------------

extern "C" void kernel_launch(void* const* d_in, const int* in_sizes, int n_in,
                              void* d_out, int out_size, void* d_ws, size_t ws_size,
                              hipStream_t stream) {
  const float* x   = (const float*)d_in[0];
  const float* Wq  = (const float*)d_in[1];
  const float* bq  = (const float*)d_in[2];
  const float* Wk  = (const float*)d_in[3];
  const float* bk  = (const float*)d_in[4];
  const float* Wv  = (const float*)d_in[5];
  const float* bv  = (const float*)d_in[6];
  const float* Wo  = (const float*)d_in[7];
  const float* bo  = (const float*)d_in[8];
  const float* rel = (const float*)d_in[9];

  const size_t MB = 1024 * 1024;
  char* ws = (char*)d_ws;
  u16*   xb    = (u16*)(ws);                 // 8MB; reused for attn O after QKV GEMM
  u16*   Wt    = (u16*)(ws + 8 * MB);        // 4096x1024 bf16 (Wq^T|Wk^T|Wv^T|Wo^T)
  u16*   qkvb  = (u16*)(ws + 16 * MB);       // 4096x3072 bf16 (V region unused)
  u16*   vtb   = (u16*)(ws + 40 * MB);       // 4096x1024 bf16 (transposed V)
  u16*   relbb = (u16*)(ws + 48 * MB);       // 1024x64 bf16
  float* bqkv  = (float*)(ws + 49 * MB);     // 3072 f32
  u16*   Ob    = xb;

  // 1) conversions + packs (fused)
  k_f32_to_bf16<<<4096, 256, 0, stream>>>(x, xb, 1048576);
  k_prep_small<<<76, 256, 0, stream>>>(rel, relbb, bq, bk, bv, bqkv);
  k_transpose_w4<<<dim3(32, 32, 4), 256, 0, stream>>>(Wq, Wk, Wv, Wo, Wt);

  // 2) fused QKV projection; V block written directly transposed into vtb
  k_gemm<2><<<dim3(24, 32), 256, 0, stream>>>(xb, Wt, bqkv, qkvb, vtb, 4096, 3072, 1024);

  // 3) attention: 2048 blocks x 128 threads (2 waves, 32 q-rows), 8 blocks/CU
  k_attn<<<2048, 128, 0, stream>>>(qkvb, vtb, relbb, Ob);

  // 4) output projection -> fp32 d_out
  k_gemm<0><<<dim3(8, 32), 256, 0, stream>>>(Ob, Wt + 3 * MB, bo, d_out, nullptr, 4096, 1024, 1024);
}

// Round 6
// 185.934 us; speedup vs baseline: 1.0383x; 1.0383x over previous
//
#include <hip/hip_runtime.h>

typedef unsigned short u16;
typedef __attribute__((ext_vector_type(8))) __bf16 bf16x8;
typedef __attribute__((ext_vector_type(4))) float f32x4;
typedef __attribute__((ext_vector_type(4))) u16 u16x4;

// ---------------- helpers ----------------

__device__ __forceinline__ u16 f2bf(float f) {
  unsigned u = __float_as_uint(f);
  u += 0x7fff + ((u >> 16) & 1);   // RNE
  return (u16)(u >> 16);
}

__device__ __forceinline__ f32x4 mfma16(bf16x8 a, bf16x8 b, f32x4 c) {
  return __builtin_amdgcn_mfma_f32_16x16x32_bf16(a, b, c, 0, 0, 0);
}

__device__ __forceinline__ void gload16(const void* g, void* l) {
  __builtin_amdgcn_global_load_lds(
      (__attribute__((address_space(1))) unsigned int*)(const_cast<void*>(g)),
      (__attribute__((address_space(3))) unsigned int*)l, 16, 0, 0);
}

// ---------------- prep kernels (fused) ----------------

__global__ void k_f32_to_bf16(const float* __restrict__ in, u16* __restrict__ out, int n4) {
  int i = blockIdx.x * blockDim.x + threadIdx.x;
  if (i < n4) {
    float4 v = reinterpret_cast<const float4*>(in)[i];
    u16x4 o;
    o.x = f2bf(v.x); o.y = f2bf(v.y); o.z = f2bf(v.z); o.w = f2bf(v.w);
    reinterpret_cast<u16x4*>(out)[i] = o;
  }
}

// rel f32->bf16 (blocks 0..63) + bias pack (blocks 64..75) in one launch
__global__ void k_prep_small(const float* __restrict__ rel, u16* __restrict__ relb,
                             const float* __restrict__ bq, const float* __restrict__ bk,
                             const float* __restrict__ bv, float* __restrict__ bias) {
  const int bx = blockIdx.x, t = threadIdx.x;
  if (bx < 64) {
    int i = bx * 256 + t;          // 16384 float4 chunks
    float4 v = reinterpret_cast<const float4*>(rel)[i];
    u16x4 o;
    o.x = f2bf(v.x); o.y = f2bf(v.y); o.z = f2bf(v.z); o.w = f2bf(v.w);
    reinterpret_cast<u16x4*>(relb)[i] = o;
  } else {
    int i = (bx - 64) * 256 + t;
    if (i < 3072) bias[i] = (i < 1024) ? bq[i] : (i < 2048 ? bk[i - 1024] : bv[i - 2048]);
  }
}

// Wt[n][k] = W[k][n], fp32 -> bf16, all four weights in one launch (grid.z = 4)
__global__ void k_transpose_w4(const float* __restrict__ W0, const float* __restrict__ W1,
                               const float* __restrict__ W2, const float* __restrict__ W3,
                               u16* __restrict__ outbase) {
  __shared__ float tile[32][33];
  const int z = blockIdx.z;
  const float* in = (z == 0) ? W0 : (z == 1) ? W1 : (z == 2) ? W2 : W3;
  u16* out = outbase + (size_t)z * 1024 * 1024;
  const int r0 = blockIdx.y * 32, c0 = blockIdx.x * 32;
  const int t = threadIdx.x;
  for (int i = t; i < 1024; i += 256) {
    int r = i >> 5, c = i & 31;
    tile[r][c] = in[(size_t)(r0 + r) * 1024 + c0 + c];
  }
  __syncthreads();
  for (int i = t; i < 1024; i += 256) {
    int r = i >> 5, c = i & 31;
    out[(size_t)(c0 + r) * 1024 + r0 + c] = f2bf(tile[c][r]);
  }
}

// ---------------- GEMM: C[m][n] = sum_k A[m][k]*B[n][k] + bias[n] ----------------
// MODE 0: fp32 output. MODE 2: bf16 output, and cols >= 2048 (the V block of the
// fused QKV GEMM) are routed to Vaux in transposed layout
// Vaux[(b*1024 + (col-2048))*1024 + s], replacing the separate transpose kernel.

template<int MODE>
__global__ __launch_bounds__(256) void k_gemm(
    const u16* __restrict__ A, const u16* __restrict__ B,
    const float* __restrict__ bias, void* __restrict__ Cout,
    u16* __restrict__ Vaux, int M, int N, int Kd)
{
  __shared__ u16 Alds[128 * 32];
  __shared__ u16 Blds[128 * 32];
  const int t = threadIdx.x;
  const int lane = t & 63, wid = t >> 6;
  const int wr = wid >> 1, wc = wid & 1;
  const int l15 = lane & 15, lg = lane >> 4;
  const int m0 = blockIdx.y * 128, n0 = blockIdx.x * 128;
  const int trow = t >> 2;
  const int tcol = (t & 3) * 8;

  const f32x4 fzero = {0.f, 0.f, 0.f, 0.f};
  f32x4 acc[4][4];
#pragma unroll
  for (int i = 0; i < 4; i++)
#pragma unroll
    for (int j = 0; j < 4; j++) acc[i][j] = fzero;

  const size_t aoff0 = (size_t)(m0 + trow) * Kd + tcol;
  const size_t aoff1 = (size_t)(m0 + 64 + trow) * Kd + tcol;
  const size_t boff0 = (size_t)(n0 + trow) * Kd + tcol;
  const size_t boff1 = (size_t)(n0 + 64 + trow) * Kd + tcol;
  u16* la0 = Alds + wid * 512;
  u16* la1 = Alds + 2048 + wid * 512;
  u16* lb0 = Blds + wid * 512;
  u16* lb1 = Blds + 2048 + wid * 512;

  for (int k0 = 0; k0 < Kd; k0 += 32) {
    gload16(A + aoff0 + k0, la0);
    gload16(A + aoff1 + k0, la1);
    gload16(B + boff0 + k0, lb0);
    gload16(B + boff1 + k0, lb1);
    __syncthreads();
    bf16x8 av[4], bv[4];
#pragma unroll
    for (int mi = 0; mi < 4; mi++)
      av[mi] = *reinterpret_cast<const bf16x8*>(Alds + (wr * 64 + mi * 16 + l15) * 32 + lg * 8);
#pragma unroll
    for (int ni = 0; ni < 4; ni++)
      bv[ni] = *reinterpret_cast<const bf16x8*>(Blds + (wc * 64 + ni * 16 + l15) * 32 + lg * 8);
#pragma unroll
    for (int mi = 0; mi < 4; mi++)
#pragma unroll
      for (int ni = 0; ni < 4; ni++)
        acc[mi][ni] = mfma16(av[mi], bv[ni], acc[mi][ni]);
    __syncthreads();
  }

#pragma unroll
  for (int mi = 0; mi < 4; mi++) {
#pragma unroll
    for (int ni = 0; ni < 4; ni++) {
      const int col = n0 + wc * 64 + ni * 16 + l15;
      const float bcol = bias[col];
#pragma unroll
      for (int r = 0; r < 4; r++) {
        const int row = m0 + wr * 64 + mi * 16 + lg * 4 + r;
        const float v = acc[mi][ni][r] + bcol;
        if (MODE == 0) {
          ((float*)Cout)[(size_t)row * N + col] = v;
        } else {
          if (col < 2048) {
            ((u16*)Cout)[(size_t)row * N + col] = f2bf(v);
          } else {
            const int bb = row >> 10, ss = row & 1023;
            Vaux[((size_t)bb * 1024 + (col - 2048)) * 1024 + ss] = f2bf(v);
          }
        }
      }
    }
  }
}

// ---------------- attention ----------------
// v7: governing law from rounds 0/3/5: dur ~= (stage->sync iterations per CU)
// x ~1.6-1.9us, nearly independent of concurrency. So: HALVE the iteration
// count at constant occupancy. Round-3 skeleton (4 waves / 64 q-rows / 1024
// blocks / balanced mapping), but each barrier-iteration stages TWO 64-k tiles
// (8 gload16/thread), then computes both tiles back-to-back from LDS.
// Per-CU sync-iterations: 34 -> 18 (balanced: sums of ceil(nk/2) == 18 for
// every residue class). The vmcnt-drain latency amortizes over 2x compute.
// LDS trimmed to fit 4 blocks/CU by using the shuffle rel-combine (validated
// rounds 1/4/5; round-5 measured it CHEAPER per iteration than the W-band:
// 1.60 vs 1.88 us/iter, conflicts 0): K 2x8K + V 2x8K + P 4x2K = 40960 B.
// rel loads stay inline+immediately consumed (round-2 lesson); no gload_lds
// prefetch shares the vmcnt queue with them (round-1 lesson).

__global__ __launch_bounds__(256, 4) void k_attn(
    const u16* __restrict__ qkv,   // (4096, 3072): Q|K|V
    const u16* __restrict__ vt,    // (64*64, 1024): Vt[bh*64+d][s]
    const u16* __restrict__ relb,  // (1024, 64)
    u16* __restrict__ Oout)        // (4096, 1024)
{
  __shared__ u16 Klds[2][64 * 64];   // 2 x 8 KB, swizzled: byte = row*128 + (cb ^ ((row&7)<<4))
  __shared__ u16 Vlds[2][64 * 64];   // 2 x 8 KB, same swizzle (rows = d)
  __shared__ u16 Plds[4][16 * 64];   // 8 KB, per-wave P (bf16), swizzled rows of 128B

  const int t = threadIdx.x;
  const int lane = t & 63, w = t >> 6;
  const int l15 = lane & 15, lg = lane >> 4;
  const int blk = blockIdx.x;
  const int bh = blk & 63;             // blocks of a bh share an XCD (blk%8 == bh%8)
  // balanced q-tile mapping: groups {g, g+4, g+8, g+12} co-reside on one CU;
  // qbt per quarter j: {15-r, 8+r, 7-r, r} -> per-CU sum(ceil(nk/2)) == 18.
  const int g = blk >> 6;
  const int jq = g >> 2, rq = g & 3;
  const int qbt = (jq == 0) ? (15 - rq) : (jq == 1) ? (8 + rq) : (jq == 2) ? (7 - rq) : rq;
  const int b = bh >> 4, h = bh & 15;
  const int qb = qbt * 64;
  const int qw = qb + w * 16;

  u16* Pb = Plds[w];
  const f32x4 fzero = {0.f, 0.f, 0.f, 0.f};

  // Q A-fragments, held in registers
  const size_t qrow = (size_t)(b * 1024 + qw + l15) * 3072 + h * 64;
  bf16x8 aQ0 = *reinterpret_cast<const bf16x8*>(qkv + qrow + lg * 8);
  bf16x8 aQ1 = *reinterpret_cast<const bf16x8*>(qkv + qrow + 32 + lg * 8);

  f32x4 oacc[4];
  float l_r[4];
#pragma unroll
  for (int r = 0; r < 4; r++) { oacc[r] = fzero; l_r[r] = 0.f; }

  // staging: thread t stages chunks t and t+256 (16B each) per tile; dest is
  // linear, source col inverse-swizzled so LDS holds the swizzled layout.
  const int srow = t >> 3;
  const int scb = ((t & 7) * 16) ^ ((srow & 7) << 4);
  const u16* Ks0 = qkv + (size_t)(b * 1024 + srow) * 3072 + 1024 + h * 64 + (scb >> 1);
  const u16* Ks1 = Ks0 + 32 * 3072;
  const u16* Vs0 = vt + (size_t)(bh * 64 + srow) * 1024 + (scb >> 1);
  const u16* Vs1 = Vs0 + 32 * 1024;

  const int nk = qbt + 1;              // uniform trip count across the 4 waves
  const float SC = 0.125f * 1.44269504f;   // fold 1/sqrt(D) and log2(e)

  // one k-tile's compute, entirely from LDS buf p (+ inline rel loads)
  auto compute = [&](int p, int k0) {
    const char* Kb = (const char*)Klds[p];
    const char* Vb = (const char*)Vlds[p];

    // content scores: 16 q x 64 k from swizzled Klds[p]
    f32x4 sc4[4];
#pragma unroll
    for (int tt = 0; tt < 4; tt++) sc4[tt] = fzero;
#pragma unroll
    for (int tt = 0; tt < 4; tt++) {
      const int row = tt * 16 + l15;
      const int sw = (row & 7) << 4;
      bf16x8 b0 = *reinterpret_cast<const bf16x8*>(Kb + row * 128 + ((lg * 16) ^ sw));
      bf16x8 b1 = *reinterpret_cast<const bf16x8*>(Kb + row * 128 + ((64 + lg * 16) ^ sw));
      sc4[tt] = mfma16(aQ0, b0, sc4[tt]);
      sc4[tt] = mfma16(aQ1, b1, sc4[tt]);
    }

    // rel band: z[wj] rows = lg*4+r, cols = band pos wj*16 + l15.
    // loads inline, consumed immediately (short live ranges).
    const int rbase = 1008 + k0 - qw;
    f32x4 z[5];
#pragma unroll
    for (int wj = 0; wj < 5; wj++) {
      int rr = rbase + wj * 16 + l15;
      rr = rr < 0 ? 0 : (rr > 1023 ? 1023 : rr);   // clamped rows feed only masked entries
      const u16* rp = relb + rr * 64;
      bf16x8 b0 = *reinterpret_cast<const bf16x8*>(rp + lg * 8);
      bf16x8 b1 = *reinterpret_cast<const bf16x8*>(rp + 32 + lg * 8);
      f32x4 zz = fzero;
      zz = mfma16(aQ0, b0, zz);
      zz = mfma16(aQ1, b1, zz);
      z[wj] = zz;
    }

    // combine + mask + exp2 (defer-max: static max 0) + P write.
    // band pos needed = tt*16 + u, u = l15+15-rowi; same row as producer ->
    // within-16-group rotation (validated rounds 1/4/5).
    asm volatile("" ::: "memory");     // keep P writes after prior PV reads
#pragma unroll
    for (int r = 0; r < 4; r++) {
      const int rowi = lg * 4 + r;
      const int q = qw + rowi;
      const int u = l15 + 15 - rowi;               // in [0,30]
      const int src = (lane & 48) | (u & 15);
      float sz[5];
#pragma unroll
      for (int wj = 0; wj < 5; wj++) sz[wj] = __shfl(z[wj][r], src);
#pragma unroll
      for (int tt = 0; tt < 4; tt++) {
        const int kg = k0 + tt * 16 + l15;
        const float wv = (u & 16) ? sz[tt + 1] : sz[tt];
        const float s = (sc4[tt][r] + wv) * SC;
        const float p2 = (kg <= q) ? exp2f(s) : 0.f;
        l_r[r] += p2;
        const int cb = (32 * tt + 2 * l15) ^ ((rowi & 7) << 4);
        *(u16*)((char*)Pb + rowi * 128 + cb) = f2bf(p2);
      }
    }
    __builtin_amdgcn_wave_barrier();
    asm volatile("" ::: "memory");     // order P writes before P reads

    // PV from swizzled Plds (A) and Vlds[p] (B)
#pragma unroll
    for (int s = 0; s < 2; s++) {
      const int acb = (s * 64 + lg * 16) ^ ((l15 & 7) << 4);
      bf16x8 aP = *reinterpret_cast<const bf16x8*>((const char*)Pb + l15 * 128 + acb);
#pragma unroll
      for (int dt = 0; dt < 4; dt++) {
        const int vrow = dt * 16 + l15;
        const int vcb = (s * 64 + lg * 16) ^ ((vrow & 7) << 4);
        bf16x8 bV = *reinterpret_cast<const bf16x8*>(Vb + vrow * 128 + vcb);
        oacc[dt] = mfma16(aP, bV, oacc[dt]);
      }
    }
  };

  for (int kt = 0; kt < nk; kt += 2) {
    const int k0 = kt * 64;
    const bool two = (kt + 1 < nk);    // uniform across the block

    // stage tile kt -> buf 0 (and kt+1 -> buf 1): 8 gload16/thread max
    gload16(Ks0 + (size_t)k0 * 3072, Klds[0] + t * 8);
    gload16(Ks1 + (size_t)k0 * 3072, Klds[0] + (t + 256) * 8);
    gload16(Vs0 + k0, Vlds[0] + t * 8);
    gload16(Vs1 + k0, Vlds[0] + (t + 256) * 8);
    if (two) {
      const int k1 = k0 + 64;
      gload16(Ks0 + (size_t)k1 * 3072, Klds[1] + t * 8);
      gload16(Ks1 + (size_t)k1 * 3072, Klds[1] + (t + 256) * 8);
      gload16(Vs0 + k1, Vlds[1] + t * 8);
      gload16(Vs1 + k1, Vlds[1] + (t + 256) * 8);
    }
    __syncthreads();   // single vmcnt drain for BOTH tiles

    compute(0, k0);
    if (two) compute(1, k0 + 64);

    __syncthreads();   // all waves done with K/V/P before restaging
  }

  // epilogue: one row-sum reduce, scale, store
#pragma unroll
  for (int r = 0; r < 4; r++) {
    float l = l_r[r];
#pragma unroll
    for (int xm = 1; xm < 16; xm <<= 1) l += __shfl_xor(l, xm);
    const float inv = 1.f / l;
    const int q = qw + lg * 4 + r;
#pragma unroll
    for (int dt = 0; dt < 4; dt++)
      Oout[(size_t)(b * 1024 + q) * 1024 + h * 64 + dt * 16 + l15] = f2bf(oacc[dt][r] * inv);
  }
}

// ---------------- launcher ----------------

extern "C" void kernel_launch(void* const* d_in, const int* in_sizes, int n_in,
                              void* d_out, int out_size, void* d_ws, size_t ws_size,
                              hipStream_t stream) {
  const float* x   = (const float*)d_in[0];
  const float* Wq  = (const float*)d_in[1];
  const float* bq  = (const float*)d_in[2];
  const float* Wk  = (const float*)d_in[3];
  const float* bk  = (const float*)d_in[4];
  const float* Wv  = (const float*)d_in[5];
  const float* bv  = (const float*)d_in[6];
  const float* Wo  = (const float*)d_in[7];
  const float* bo  = (const float*)d_in[8];
  const float* rel = (const float*)d_in[9];

  const size_t MB = 1024 * 1024;
  char* ws = (char*)d_ws;
  u16*   xb    = (u16*)(ws);                 // 8MB; reused for attn O after QKV GEMM
  u16*   Wt    = (u16*)(ws + 8 * MB);        // 4096x1024 bf16 (Wq^T|Wk^T|Wv^T|Wo^T)
  u16*   qkvb  = (u16*)(ws + 16 * MB);       // 4096x3072 bf16 (V region unused)
  u16*   vtb   = (u16*)(ws + 40 * MB);       // 4096x1024 bf16 (transposed V)
  u16*   relbb = (u16*)(ws + 48 * MB);       // 1024x64 bf16
  float* bqkv  = (float*)(ws + 49 * MB);     // 3072 f32
  u16*   Ob    = xb;

  // 1) conversions + packs (fused)
  k_f32_to_bf16<<<4096, 256, 0, stream>>>(x, xb, 1048576);
  k_prep_small<<<76, 256, 0, stream>>>(rel, relbb, bq, bk, bv, bqkv);
  k_transpose_w4<<<dim3(32, 32, 4), 256, 0, stream>>>(Wq, Wk, Wv, Wo, Wt);

  // 2) fused QKV projection; V block written directly transposed into vtb
  k_gemm<2><<<dim3(24, 32), 256, 0, stream>>>(xb, Wt, bqkv, qkvb, vtb, 4096, 3072, 1024);

  // 3) attention: 1024 blocks x 4 waves, 2 k-tiles per barrier-iteration
  k_attn<<<1024, 256, 0, stream>>>(qkvb, vtb, relbb, Ob);

  // 4) output projection -> fp32 d_out
  k_gemm<0><<<dim3(8, 32), 256, 0, stream>>>(Ob, Wt + 3 * MB, bo, d_out, nullptr, 4096, 1024, 1024);
}

// Round 7
// 140.290 us; speedup vs baseline: 1.3762x; 1.3254x over previous
//
#include <hip/hip_runtime.h>

typedef unsigned short u16;
typedef __attribute__((ext_vector_type(8))) __bf16 bf16x8;
typedef __attribute__((ext_vector_type(4))) float f32x4;
typedef __attribute__((ext_vector_type(4))) u16 u16x4;

// ---------------- helpers ----------------

__device__ __forceinline__ u16 f2bf(float f) {
  unsigned u = __float_as_uint(f);
  u += 0x7fff + ((u >> 16) & 1);   // RNE
  return (u16)(u >> 16);
}

__device__ __forceinline__ f32x4 mfma16(bf16x8 a, bf16x8 b, f32x4 c) {
  return __builtin_amdgcn_mfma_f32_16x16x32_bf16(a, b, c, 0, 0, 0);
}

__device__ __forceinline__ void gload16(const void* g, void* l) {
  __builtin_amdgcn_global_load_lds(
      (__attribute__((address_space(1))) unsigned int*)(const_cast<void*>(g)),
      (__attribute__((address_space(3))) unsigned int*)l, 16, 0, 0);
}

// ---------------- prep kernels (fused) ----------------

__global__ void k_f32_to_bf16(const float* __restrict__ in, u16* __restrict__ out, int n4) {
  int i = blockIdx.x * blockDim.x + threadIdx.x;
  if (i < n4) {
    float4 v = reinterpret_cast<const float4*>(in)[i];
    u16x4 o;
    o.x = f2bf(v.x); o.y = f2bf(v.y); o.z = f2bf(v.z); o.w = f2bf(v.w);
    reinterpret_cast<u16x4*>(out)[i] = o;
  }
}

// rel f32->bf16 (blocks 0..63) + bias pack (blocks 64..75) in one launch
__global__ void k_prep_small(const float* __restrict__ rel, u16* __restrict__ relb,
                             const float* __restrict__ bq, const float* __restrict__ bk,
                             const float* __restrict__ bv, float* __restrict__ bias) {
  const int bx = blockIdx.x, t = threadIdx.x;
  if (bx < 64) {
    int i = bx * 256 + t;          // 16384 float4 chunks
    float4 v = reinterpret_cast<const float4*>(rel)[i];
    u16x4 o;
    o.x = f2bf(v.x); o.y = f2bf(v.y); o.z = f2bf(v.z); o.w = f2bf(v.w);
    reinterpret_cast<u16x4*>(relb)[i] = o;
  } else {
    int i = (bx - 64) * 256 + t;
    if (i < 3072) bias[i] = (i < 1024) ? bq[i] : (i < 2048 ? bk[i - 1024] : bv[i - 2048]);
  }
}

// Wt[n][k] = W[k][n], fp32 -> bf16, all four weights in one launch (grid.z = 4)
__global__ void k_transpose_w4(const float* __restrict__ W0, const float* __restrict__ W1,
                               const float* __restrict__ W2, const float* __restrict__ W3,
                               u16* __restrict__ outbase) {
  __shared__ float tile[32][33];
  const int z = blockIdx.z;
  const float* in = (z == 0) ? W0 : (z == 1) ? W1 : (z == 2) ? W2 : W3;
  u16* out = outbase + (size_t)z * 1024 * 1024;
  const int r0 = blockIdx.y * 32, c0 = blockIdx.x * 32;
  const int t = threadIdx.x;
  for (int i = t; i < 1024; i += 256) {
    int r = i >> 5, c = i & 31;
    tile[r][c] = in[(size_t)(r0 + r) * 1024 + c0 + c];
  }
  __syncthreads();
  for (int i = t; i < 1024; i += 256) {
    int r = i >> 5, c = i & 31;
    out[(size_t)(c0 + r) * 1024 + r0 + c] = f2bf(tile[c][r]);
  }
}

// ---------------- GEMM: C[m][n] = sum_k A[m][k]*B[n][k] + bias[n] ----------------
// v2: BK 32 -> 64 (halves the stage->drain->barrier count; the 1-3 blocks/CU
// grids are latency/barrier-bound). Same 2-barrier skeleton, 128x128 tile.
// [128][64] rows are 128 B -> 16-way bank conflict if linear, so the rows use
// the attn-proven XOR-16 swizzle: staged via pre-swizzled global source with a
// linear gload_lds dest, read back with the same XOR (2-way = free).
// MODE 0: fp32 output. MODE 2: bf16 output + cols >= 2048 (V block of the fused
// QKV GEMM) routed to Vaux transposed: Vaux[(b*1024 + (col-2048))*1024 + s].

template<int MODE>
__global__ __launch_bounds__(256) void k_gemm(
    const u16* __restrict__ A, const u16* __restrict__ B,
    const float* __restrict__ bias, void* __restrict__ Cout,
    u16* __restrict__ Vaux, int M, int N, int Kd)
{
  __shared__ u16 Alds[128 * 64];   // 16 KB, swizzled: byte = row*128 + (cb ^ ((row&7)<<4))
  __shared__ u16 Blds[128 * 64];   // 16 KB
  const int t = threadIdx.x;
  const int lane = t & 63, wid = t >> 6;
  const int wr = wid >> 1, wc = wid & 1;
  const int l15 = lane & 15, lg = lane >> 4;
  const int m0 = blockIdx.y * 128, n0 = blockIdx.x * 128;

  const f32x4 fzero = {0.f, 0.f, 0.f, 0.f};
  f32x4 acc[4][4];
#pragma unroll
  for (int i = 0; i < 4; i++)
#pragma unroll
    for (int j = 0; j < 4; j++) acc[i][j] = fzero;

  // staging: 1024 16B chunks per array; thread t stages chunks {t, t+256, t+512,
  // t+768}. chunk c: row = c>>3 (row&7 is ci-invariant), col byte = (c&7)*16,
  // source col inverse-swizzled so LDS holds the swizzled layout, linear dest.
  const int srow = t >> 3;                                  // 0..31
  const int scb  = ((t & 7) * 16) ^ ((srow & 7) << 4);      // byte offset in 128B row
  const size_t abase = (size_t)(m0 + srow) * Kd + (scb >> 1);
  const size_t bbase = (size_t)(n0 + srow) * Kd + (scb >> 1);

  for (int k0 = 0; k0 < Kd; k0 += 64) {
#pragma unroll
    for (int ci = 0; ci < 4; ci++) {
      gload16(A + abase + (size_t)(32 * ci) * Kd + k0, Alds + (t + 256 * ci) * 8);
      gload16(B + bbase + (size_t)(32 * ci) * Kd + k0, Blds + (t + 256 * ci) * 8);
    }
    __syncthreads();
#pragma unroll
    for (int kk = 0; kk < 2; kk++) {
      bf16x8 av[4], bv[4];
#pragma unroll
      for (int mi = 0; mi < 4; mi++) {
        const int row = wr * 64 + mi * 16 + l15;
        av[mi] = *reinterpret_cast<const bf16x8*>(
            (const char*)Alds + row * 128 + ((kk * 64 + lg * 16) ^ ((row & 7) << 4)));
      }
#pragma unroll
      for (int ni = 0; ni < 4; ni++) {
        const int row = wc * 64 + ni * 16 + l15;
        bv[ni] = *reinterpret_cast<const bf16x8*>(
            (const char*)Blds + row * 128 + ((kk * 64 + lg * 16) ^ ((row & 7) << 4)));
      }
#pragma unroll
      for (int mi = 0; mi < 4; mi++)
#pragma unroll
        for (int ni = 0; ni < 4; ni++)
          acc[mi][ni] = mfma16(av[mi], bv[ni], acc[mi][ni]);
    }
    __syncthreads();
  }

#pragma unroll
  for (int mi = 0; mi < 4; mi++) {
#pragma unroll
    for (int ni = 0; ni < 4; ni++) {
      const int col = n0 + wc * 64 + ni * 16 + l15;
      const float bcol = bias[col];
#pragma unroll
      for (int r = 0; r < 4; r++) {
        const int row = m0 + wr * 64 + mi * 16 + lg * 4 + r;
        const float v = acc[mi][ni][r] + bcol;
        if (MODE == 0) {
          ((float*)Cout)[(size_t)row * N + col] = v;
        } else {
          if (col < 2048) {
            ((u16*)Cout)[(size_t)row * N + col] = f2bf(v);
          } else {
            const int bb = row >> 10, ss = row & 1023;
            Vaux[((size_t)bb * 1024 + (col - 2048)) * 1024 + ss] = f2bf(v);
          }
        }
      }
    }
  }
}

// ---------------- attention ----------------
// ROUND-3 VERSION RESTORED VERBATIM (measured 64.0 us, reproduced twice).
// Evidence from rounds 1/2/4/5/6: every variant replacing the W-band LDS
// round-trip with the ds_bpermute shuffle combine ran 93-118 us regardless of
// staging structure (pure ~2700 cy/wave-tile stall: serialized bpermute chains
// + MFMA-dest read hazards). The W-band form is a compiler-scheduling local
// optimum. DO NOT restructure this kernel.

__global__ __launch_bounds__(256, 4) void k_attn(
    const u16* __restrict__ qkv,   // (4096, 3072): Q|K|V
    const u16* __restrict__ vt,    // (64*64, 1024): Vt[bh*64+d][s]
    const u16* __restrict__ relb,  // (1024, 64)
    u16* __restrict__ Oout)        // (4096, 1024)
{
  __shared__ u16 Klds[64 * 64];        // 8 KB, swizzled: byte = row*128 + (cb ^ ((row&7)<<4))
  __shared__ u16 Vlds[64 * 64];        // 8 KB, same swizzle (rows = d)
  __shared__ float Sbuf[4][16 * 84];   // 21 KB, per-wave: W band f32 (stride 84); P (bf16) aliases base

  const int t = threadIdx.x;
  const int lane = t & 63, w = t >> 6;
  const int l15 = lane & 15, lg = lane >> 4;
  const int blk = blockIdx.x;
  const int bh = blk & 63;             // blocks of a bh share an XCD (blk%8 == bh%8)
  // balanced q-tile mapping: groups {g, g+4, g+8, g+12} co-reside on one CU;
  // qbt per quarter j: {15-r, 8+r, 7-r, r} -> per-CU sum(nk) == 34 for all r.
  const int g = blk >> 6;
  const int jq = g >> 2, rq = g & 3;
  const int qbt = (jq == 0) ? (15 - rq) : (jq == 1) ? (8 + rq) : (jq == 2) ? (7 - rq) : rq;
  const int b = bh >> 4, h = bh & 15;
  const int qb = qbt * 64;
  const int qw = qb + w * 16;

  float* Wb = Sbuf[w];
  u16* Pb = (u16*)Sbuf[w];             // aliases Wb; ordering via wave_barrier fences

  const f32x4 fzero = {0.f, 0.f, 0.f, 0.f};

  // Q A-fragments, held in registers
  const size_t qrow = (size_t)(b * 1024 + qw + l15) * 3072 + h * 64;
  bf16x8 aQ0 = *reinterpret_cast<const bf16x8*>(qkv + qrow + lg * 8);
  bf16x8 aQ1 = *reinterpret_cast<const bf16x8*>(qkv + qrow + 32 + lg * 8);

  f32x4 oacc[4];
  float l_r[4];
#pragma unroll
  for (int r = 0; r < 4; r++) { oacc[r] = fzero; l_r[r] = 0.f; }

  // staging: thread t stages chunks t and t+256 (16B each) for K and V.
  // dest byte t*16 -> logical (row = t>>3, cb = (t&7)*16); source col byte is
  // inverse-swizzled so LDS holds the swizzled layout with a linear dest.
  const int srow = t >> 3;
  const int scb = ((t & 7) * 16) ^ ((srow & 7) << 4);
  const u16* Ks0 = qkv + (size_t)(b * 1024 + srow) * 3072 + 1024 + h * 64 + (scb >> 1);
  const u16* Ks1 = Ks0 + 32 * 3072;
  const u16* Vs0 = vt + (size_t)(bh * 64 + srow) * 1024 + (scb >> 1);
  const u16* Vs1 = Vs0 + 32 * 1024;
  u16* Kd0 = Klds + t * 8;  u16* Kd1 = Klds + (t + 256) * 8;
  u16* Vd0 = Vlds + t * 8;  u16* Vd1 = Vlds + (t + 256) * 8;

  const int nk = qbt + 1;              // uniform trip count across the 4 waves
  const float SC = 0.125f * 1.44269504f;   // fold 1/sqrt(D) and log2(e)

  for (int kt = 0; kt < nk; kt++) {
    const int k0 = kt * 64;
    gload16(Ks0 + (size_t)k0 * 3072, Kd0);
    gload16(Ks1 + (size_t)k0 * 3072, Kd1);
    gload16(Vs0 + k0, Vd0);
    gload16(Vs1 + k0, Vd1);
    __syncthreads();   // drains vmcnt for all waves; K/V tile ready

    // content scores: 16 q x 64 k from swizzled Klds
    f32x4 sc4[4];
#pragma unroll
    for (int tt = 0; tt < 4; tt++) sc4[tt] = fzero;
#pragma unroll
    for (int tt = 0; tt < 4; tt++) {
      const int row = tt * 16 + l15;
      const int sw = (row & 7) << 4;
      bf16x8 b0 = *reinterpret_cast<const bf16x8*>((const char*)Klds + row * 128 + ((lg * 16) ^ sw));
      bf16x8 b1 = *reinterpret_cast<const bf16x8*>((const char*)Klds + row * 128 + ((64 + lg * 16) ^ sw));
      sc4[tt] = mfma16(aQ0, b0, sc4[tt]);
      sc4[tt] = mfma16(aQ1, b1, sc4[tt]);
    }

    // rel band: W[q][j] = Q[q]·rel[rbase+j], j in [0,80); direct global (L2-hot)
    const int rbase = 1008 + k0 - qw;
#pragma unroll
    for (int wj = 0; wj < 5; wj++) {
      int rr = rbase + wj * 16 + l15;
      rr = rr < 0 ? 0 : (rr > 1023 ? 1023 : rr);   // clamped rows feed only masked entries
      const u16* rp = relb + rr * 64;
      bf16x8 b0 = *reinterpret_cast<const bf16x8*>(rp + lg * 8);
      bf16x8 b1 = *reinterpret_cast<const bf16x8*>(rp + 32 + lg * 8);
      f32x4 z = fzero;
      z = mfma16(aQ0, b0, z);
      z = mfma16(aQ1, b1, z);
#pragma unroll
      for (int r = 0; r < 4; r++)
        Wb[(lg * 4 + r) * 84 + wj * 16 + l15] = z[r];
    }
    __builtin_amdgcn_wave_barrier();

    // combine + mask + exp2 (defer-max: static max 0); per-lane l partials
    float pvv[4][4];
#pragma unroll
    for (int r = 0; r < 4; r++) {
      const int rowi = lg * 4 + r;
      const int q = qw + rowi;
      const float* wrow = Wb + rowi * 84 + (15 - rowi);
#pragma unroll
      for (int tt = 0; tt < 4; tt++) {
        const int kg = k0 + tt * 16 + l15;
        float s = (sc4[tt][r] + wrow[tt * 16 + l15]) * SC;
        s = (kg <= q) ? s : -1e30f;
        float p = exp2f(s);
        pvv[tt][r] = p;
        l_r[r] += p;
      }
    }
    __builtin_amdgcn_wave_barrier();
    asm volatile("" ::: "memory");     // order W-reads before aliased P-writes

    // P -> LDS bf16, swizzled rows of 128B
#pragma unroll
    for (int tt = 0; tt < 4; tt++)
#pragma unroll
      for (int r = 0; r < 4; r++) {
        const int rowi = lg * 4 + r;
        const int cb = (32 * tt + 2 * l15) ^ ((rowi & 7) << 4);
        *(u16*)((char*)Pb + rowi * 128 + cb) = f2bf(pvv[tt][r]);
      }
    __builtin_amdgcn_wave_barrier();

    // PV from swizzled Plds (A) and Vlds (B)
#pragma unroll
    for (int s = 0; s < 2; s++) {
      const int acb = (s * 64 + lg * 16) ^ ((l15 & 7) << 4);
      bf16x8 aP = *reinterpret_cast<const bf16x8*>((const char*)Pb + l15 * 128 + acb);
#pragma unroll
      for (int dt = 0; dt < 4; dt++) {
        const int vrow = dt * 16 + l15;
        const int vcb = (s * 64 + lg * 16) ^ ((vrow & 7) << 4);
        bf16x8 bV = *reinterpret_cast<const bf16x8*>((const char*)Vlds + vrow * 128 + vcb);
        oacc[dt] = mfma16(aP, bV, oacc[dt]);
      }
    }
    __syncthreads();   // all waves done with K/V/P before restaging
  }

  // epilogue: one row-sum reduce, scale, store
#pragma unroll
  for (int r = 0; r < 4; r++) {
    float l = l_r[r];
#pragma unroll
    for (int xm = 1; xm < 16; xm <<= 1) l += __shfl_xor(l, xm);
    const float inv = 1.f / l;
    const int q = qw + lg * 4 + r;
#pragma unroll
    for (int dt = 0; dt < 4; dt++)
      Oout[(size_t)(b * 1024 + q) * 1024 + h * 64 + dt * 16 + l15] = f2bf(oacc[dt][r] * inv);
  }
}

// ---------------- launcher ----------------

extern "C" void kernel_launch(void* const* d_in, const int* in_sizes, int n_in,
                              void* d_out, int out_size, void* d_ws, size_t ws_size,
                              hipStream_t stream) {
  const float* x   = (const float*)d_in[0];
  const float* Wq  = (const float*)d_in[1];
  const float* bq  = (const float*)d_in[2];
  const float* Wk  = (const float*)d_in[3];
  const float* bk  = (const float*)d_in[4];
  const float* Wv  = (const float*)d_in[5];
  const float* bv  = (const float*)d_in[6];
  const float* Wo  = (const float*)d_in[7];
  const float* bo  = (const float*)d_in[8];
  const float* rel = (const float*)d_in[9];

  const size_t MB = 1024 * 1024;
  char* ws = (char*)d_ws;
  u16*   xb    = (u16*)(ws);                 // 8MB; reused for attn O after QKV GEMM
  u16*   Wt    = (u16*)(ws + 8 * MB);        // 4096x1024 bf16 (Wq^T|Wk^T|Wv^T|Wo^T)
  u16*   qkvb  = (u16*)(ws + 16 * MB);       // 4096x3072 bf16 (V region unused)
  u16*   vtb   = (u16*)(ws + 40 * MB);       // 4096x1024 bf16 (transposed V)
  u16*   relbb = (u16*)(ws + 48 * MB);       // 1024x64 bf16
  float* bqkv  = (float*)(ws + 49 * MB);     // 3072 f32
  u16*   Ob    = xb;

  // 1) conversions + packs (fused)
  k_f32_to_bf16<<<4096, 256, 0, stream>>>(x, xb, 1048576);
  k_prep_small<<<76, 256, 0, stream>>>(rel, relbb, bq, bk, bv, bqkv);
  k_transpose_w4<<<dim3(32, 32, 4), 256, 0, stream>>>(Wq, Wk, Wv, Wo, Wt);

  // 2) fused QKV projection (BK=64); V block written directly transposed into vtb
  k_gemm<2><<<dim3(24, 32), 256, 0, stream>>>(xb, Wt, bqkv, qkvb, vtb, 4096, 3072, 1024);

  // 3) attention: round-3 proven kernel (64 us)
  k_attn<<<1024, 256, 0, stream>>>(qkvb, vtb, relbb, Ob);

  // 4) output projection (BK=64) -> fp32 d_out
  k_gemm<0><<<dim3(8, 32), 256, 0, stream>>>(Ob, Wt + 3 * MB, bo, d_out, nullptr, 4096, 1024, 1024);
}

// Round 8
// 139.011 us; speedup vs baseline: 1.3888x; 1.0092x over previous
//
#include <hip/hip_runtime.h>

typedef unsigned short u16;
typedef __attribute__((ext_vector_type(8))) __bf16 bf16x8;
typedef __attribute__((ext_vector_type(4))) float f32x4;
typedef __attribute__((ext_vector_type(4))) u16 u16x4;

// ---------------- helpers ----------------

__device__ __forceinline__ u16 f2bf(float f) {
  unsigned u = __float_as_uint(f);
  u += 0x7fff + ((u >> 16) & 1);   // RNE
  return (u16)(u >> 16);
}

__device__ __forceinline__ f32x4 mfma16(bf16x8 a, bf16x8 b, f32x4 c) {
  return __builtin_amdgcn_mfma_f32_16x16x32_bf16(a, b, c, 0, 0, 0);
}

__device__ __forceinline__ void gload16(const void* g, void* l) {
  __builtin_amdgcn_global_load_lds(
      (__attribute__((address_space(1))) unsigned int*)(const_cast<void*>(g)),
      (__attribute__((address_space(3))) unsigned int*)l, 16, 0, 0);
}

// ---------------- fused prep kernel ----------------
// blocks [0,4096):     x f32 -> bf16 (1048576 float4 chunks)
// blocks [4096,8192):  W transpose+convert, z = (bx-4096)>>10, 32x32 tiles
// blocks [8192,8256):  rel f32 -> bf16
// blocks [8256,8268):  bias pack

__global__ void k_prep_all(const float* __restrict__ x, u16* __restrict__ xb,
                           const float* __restrict__ W0, const float* __restrict__ W1,
                           const float* __restrict__ W2, const float* __restrict__ W3,
                           u16* __restrict__ Wt,
                           const float* __restrict__ rel, u16* __restrict__ relb,
                           const float* __restrict__ bq, const float* __restrict__ bk,
                           const float* __restrict__ bv, float* __restrict__ bias) {
  __shared__ float tile[32][33];
  const int bx = blockIdx.x, t = threadIdx.x;
  if (bx < 4096) {
    int i = bx * 256 + t;
    float4 v = reinterpret_cast<const float4*>(x)[i];
    u16x4 o;
    o.x = f2bf(v.x); o.y = f2bf(v.y); o.z = f2bf(v.z); o.w = f2bf(v.w);
    reinterpret_cast<u16x4*>(xb)[i] = o;
  } else if (bx < 8192) {
    const int id = bx - 4096;
    const int z = id >> 10;
    const float* in = (z == 0) ? W0 : (z == 1) ? W1 : (z == 2) ? W2 : W3;
    u16* out = Wt + (size_t)z * 1024 * 1024;
    const int r0 = ((id >> 5) & 31) * 32, c0 = (id & 31) * 32;
    for (int i = t; i < 1024; i += 256) {
      int r = i >> 5, c = i & 31;
      tile[r][c] = in[(size_t)(r0 + r) * 1024 + c0 + c];
    }
    __syncthreads();
    for (int i = t; i < 1024; i += 256) {
      int r = i >> 5, c = i & 31;
      out[(size_t)(c0 + r) * 1024 + r0 + c] = f2bf(tile[c][r]);
    }
  } else if (bx < 8256) {
    int i = (bx - 8192) * 256 + t;
    float4 v = reinterpret_cast<const float4*>(rel)[i];
    u16x4 o;
    o.x = f2bf(v.x); o.y = f2bf(v.y); o.z = f2bf(v.z); o.w = f2bf(v.w);
    reinterpret_cast<u16x4*>(relb)[i] = o;
  } else {
    int i = (bx - 8256) * 256 + t;
    if (i < 3072) bias[i] = (i < 1024) ? bq[i] : (i < 2048 ? bk[i - 1024] : bv[i - 2048]);
  }
}

// ---------------- GEMM: C[m][n] = sum_k A[m][k]*B[n][k] + bias[n] ----------------
// BK=64, 2-barrier skeleton, 128xBN tile, XOR-16 swizzled LDS rows (staged via
// pre-swizzled global source + linear gload_lds dest; read back with same XOR).
// BN template: 128 (QKV, 768 blocks = 3/CU) or 64 (Wo, 512 blocks = 2/CU --
// doubles inter-block latency overlap for the latency-bound 1-block/CU case).
// MODE 0: fp32 output. MODE 2: bf16 output + cols >= 2048 (V block of the fused
// QKV GEMM) routed to Vaux transposed: Vaux[(b*1024 + (col-2048))*1024 + s].

template<int MODE, int BN>
__global__ __launch_bounds__(256) void k_gemm(
    const u16* __restrict__ A, const u16* __restrict__ B,
    const float* __restrict__ bias, void* __restrict__ Cout,
    u16* __restrict__ Vaux, int M, int N, int Kd)
{
  constexpr int NF = BN / 32;      // N fragments per wave (4 or 2)
  __shared__ u16 Alds[128 * 64];   // 16 KB, swizzled: byte = row*128 + (cb ^ ((row&7)<<4))
  __shared__ u16 Blds[BN * 64];
  const int t = threadIdx.x;
  const int lane = t & 63, wid = t >> 6;
  const int wr = wid >> 1, wc = wid & 1;
  const int l15 = lane & 15, lg = lane >> 4;
  const int m0 = blockIdx.y * 128, n0 = blockIdx.x * BN;

  const f32x4 fzero = {0.f, 0.f, 0.f, 0.f};
  f32x4 acc[4][NF];
#pragma unroll
  for (int i = 0; i < 4; i++)
#pragma unroll
    for (int j = 0; j < NF; j++) acc[i][j] = fzero;

  // staging: thread t stages A chunks {t+256*ci, ci<4}, B chunks {t+256*ci, ci<NF}.
  // chunk c: row = c>>3 (row&7 is ci-invariant), col byte = (c&7)*16, source col
  // inverse-swizzled so LDS holds the swizzled layout with a linear dest.
  const int srow = t >> 3;                                  // 0..31
  const int scb  = ((t & 7) * 16) ^ ((srow & 7) << 4);      // byte offset in 128B row
  const size_t abase = (size_t)(m0 + srow) * Kd + (scb >> 1);
  const size_t bbase = (size_t)(n0 + srow) * Kd + (scb >> 1);

  for (int k0 = 0; k0 < Kd; k0 += 64) {
#pragma unroll
    for (int ci = 0; ci < 4; ci++)
      gload16(A + abase + (size_t)(32 * ci) * Kd + k0, Alds + (t + 256 * ci) * 8);
#pragma unroll
    for (int ci = 0; ci < NF; ci++)
      gload16(B + bbase + (size_t)(32 * ci) * Kd + k0, Blds + (t + 256 * ci) * 8);
    __syncthreads();
#pragma unroll
    for (int kk = 0; kk < 2; kk++) {
      bf16x8 av[4], bv[NF];
#pragma unroll
      for (int mi = 0; mi < 4; mi++) {
        const int row = wr * 64 + mi * 16 + l15;
        av[mi] = *reinterpret_cast<const bf16x8*>(
            (const char*)Alds + row * 128 + ((kk * 64 + lg * 16) ^ ((row & 7) << 4)));
      }
#pragma unroll
      for (int ni = 0; ni < NF; ni++) {
        const int row = wc * (BN / 2) + ni * 16 + l15;
        bv[ni] = *reinterpret_cast<const bf16x8*>(
            (const char*)Blds + row * 128 + ((kk * 64 + lg * 16) ^ ((row & 7) << 4)));
      }
#pragma unroll
      for (int mi = 0; mi < 4; mi++)
#pragma unroll
        for (int ni = 0; ni < NF; ni++)
          acc[mi][ni] = mfma16(av[mi], bv[ni], acc[mi][ni]);
    }
    __syncthreads();
  }

#pragma unroll
  for (int mi = 0; mi < 4; mi++) {
#pragma unroll
    for (int ni = 0; ni < NF; ni++) {
      const int col = n0 + wc * (BN / 2) + ni * 16 + l15;
      const float bcol = bias[col];
#pragma unroll
      for (int r = 0; r < 4; r++) {
        const int row = m0 + wr * 64 + mi * 16 + lg * 4 + r;
        const float v = acc[mi][ni][r] + bcol;
        if (MODE == 0) {
          ((float*)Cout)[(size_t)row * N + col] = v;
        } else {
          if (col < 2048) {
            ((u16*)Cout)[(size_t)row * N + col] = f2bf(v);
          } else {
            const int bb = row >> 10, ss = row & 1023;
            Vaux[((size_t)bb * 1024 + (col - 2048)) * 1024 + ss] = f2bf(v);
          }
        }
      }
    }
  }
}

// ---------------- attention ----------------
// Round-3 structure (64.0 us, reproduced 3x): single-buffered stage->sync->
// compute, W-band LDS combine (the ds_bpermute shuffle combine is a proven
// ~40us regression -- rounds 1/2/4/5/6). ONE delta this round: the 10 rel
// register loads are issued BEFORE the K/V staging + barrier, so the barrier's
// vmcnt(0) drain lands them for free -- the rel phase becomes pure MFMA +
// LDS writes with zero exposed L2 latency. (This hoist was only ever tested
// together with the shuffle combine (r2); the shuffle is exonerated as the
// culprit there.) Everything else byte-identical. Revert criterion: VGPR>=128
// or FETCH>=14MB (spill) or k_attn > 66us.

__global__ __launch_bounds__(256, 4) void k_attn(
    const u16* __restrict__ qkv,   // (4096, 3072): Q|K|V
    const u16* __restrict__ vt,    // (64*64, 1024): Vt[bh*64+d][s]
    const u16* __restrict__ relb,  // (1024, 64)
    u16* __restrict__ Oout)        // (4096, 1024)
{
  __shared__ u16 Klds[64 * 64];        // 8 KB, swizzled: byte = row*128 + (cb ^ ((row&7)<<4))
  __shared__ u16 Vlds[64 * 64];        // 8 KB, same swizzle (rows = d)
  __shared__ float Sbuf[4][16 * 84];   // 21 KB, per-wave: W band f32 (stride 84); P (bf16) aliases base

  const int t = threadIdx.x;
  const int lane = t & 63, w = t >> 6;
  const int l15 = lane & 15, lg = lane >> 4;
  const int blk = blockIdx.x;
  const int bh = blk & 63;             // blocks of a bh share an XCD (blk%8 == bh%8)
  // balanced q-tile mapping: groups {g, g+4, g+8, g+12} co-reside on one CU;
  // qbt per quarter j: {15-r, 8+r, 7-r, r} -> per-CU sum(nk) == 34 for all r.
  const int g = blk >> 6;
  const int jq = g >> 2, rq = g & 3;
  const int qbt = (jq == 0) ? (15 - rq) : (jq == 1) ? (8 + rq) : (jq == 2) ? (7 - rq) : rq;
  const int b = bh >> 4, h = bh & 15;
  const int qb = qbt * 64;
  const int qw = qb + w * 16;

  float* Wb = Sbuf[w];
  u16* Pb = (u16*)Sbuf[w];             // aliases Wb; ordering via wave_barrier fences

  const f32x4 fzero = {0.f, 0.f, 0.f, 0.f};

  // Q A-fragments, held in registers
  const size_t qrow = (size_t)(b * 1024 + qw + l15) * 3072 + h * 64;
  bf16x8 aQ0 = *reinterpret_cast<const bf16x8*>(qkv + qrow + lg * 8);
  bf16x8 aQ1 = *reinterpret_cast<const bf16x8*>(qkv + qrow + 32 + lg * 8);

  f32x4 oacc[4];
  float l_r[4];
#pragma unroll
  for (int r = 0; r < 4; r++) { oacc[r] = fzero; l_r[r] = 0.f; }

  // staging: thread t stages chunks t and t+256 (16B each) for K and V.
  // dest byte t*16 -> logical (row = t>>3, cb = (t&7)*16); source col byte is
  // inverse-swizzled so LDS holds the swizzled layout with a linear dest.
  const int srow = t >> 3;
  const int scb = ((t & 7) * 16) ^ ((srow & 7) << 4);
  const u16* Ks0 = qkv + (size_t)(b * 1024 + srow) * 3072 + 1024 + h * 64 + (scb >> 1);
  const u16* Ks1 = Ks0 + 32 * 3072;
  const u16* Vs0 = vt + (size_t)(bh * 64 + srow) * 1024 + (scb >> 1);
  const u16* Vs1 = Vs0 + 32 * 1024;
  u16* Kd0 = Klds + t * 8;  u16* Kd1 = Klds + (t + 256) * 8;
  u16* Vd0 = Vlds + t * 8;  u16* Vd1 = Vlds + (t + 256) * 8;

  const int nk = qbt + 1;              // uniform trip count across the 4 waves
  const float SC = 0.125f * 1.44269504f;   // fold 1/sqrt(D) and log2(e)

  for (int kt = 0; kt < nk; kt++) {
    const int k0 = kt * 64;

    // rel B-fragments: issued BEFORE staging+barrier; the barrier's vmcnt(0)
    // drain guarantees they are in-register afterwards at zero extra cost.
    const int rbase = 1008 + k0 - qw;
    bf16x8 rb0[5], rb1[5];
#pragma unroll
    for (int wj = 0; wj < 5; wj++) {
      int rr = rbase + wj * 16 + l15;
      rr = rr < 0 ? 0 : (rr > 1023 ? 1023 : rr);   // clamped rows feed only masked entries
      const u16* rp = relb + rr * 64;
      rb0[wj] = *reinterpret_cast<const bf16x8*>(rp + lg * 8);
      rb1[wj] = *reinterpret_cast<const bf16x8*>(rp + 32 + lg * 8);
    }

    gload16(Ks0 + (size_t)k0 * 3072, Kd0);
    gload16(Ks1 + (size_t)k0 * 3072, Kd1);
    gload16(Vs0 + k0, Vd0);
    gload16(Vs1 + k0, Vd1);
    __syncthreads();   // drains vmcnt for all waves; K/V tile + rel regs ready

    // content scores: 16 q x 64 k from swizzled Klds
    f32x4 sc4[4];
#pragma unroll
    for (int tt = 0; tt < 4; tt++) sc4[tt] = fzero;
#pragma unroll
    for (int tt = 0; tt < 4; tt++) {
      const int row = tt * 16 + l15;
      const int sw = (row & 7) << 4;
      bf16x8 b0 = *reinterpret_cast<const bf16x8*>((const char*)Klds + row * 128 + ((lg * 16) ^ sw));
      bf16x8 b1 = *reinterpret_cast<const bf16x8*>((const char*)Klds + row * 128 + ((64 + lg * 16) ^ sw));
      sc4[tt] = mfma16(aQ0, b0, sc4[tt]);
      sc4[tt] = mfma16(aQ1, b1, sc4[tt]);
    }

    // rel band: W[q][j] = Q[q]·rel[rbase+j], j in [0,80); MFMA from registers
#pragma unroll
    for (int wj = 0; wj < 5; wj++) {
      f32x4 z = fzero;
      z = mfma16(aQ0, rb0[wj], z);
      z = mfma16(aQ1, rb1[wj], z);
#pragma unroll
      for (int r = 0; r < 4; r++)
        Wb[(lg * 4 + r) * 84 + wj * 16 + l15] = z[r];
    }
    __builtin_amdgcn_wave_barrier();

    // combine + mask + exp2 (defer-max: static max 0); per-lane l partials
    float pvv[4][4];
#pragma unroll
    for (int r = 0; r < 4; r++) {
      const int rowi = lg * 4 + r;
      const int q = qw + rowi;
      const float* wrow = Wb + rowi * 84 + (15 - rowi);
#pragma unroll
      for (int tt = 0; tt < 4; tt++) {
        const int kg = k0 + tt * 16 + l15;
        float s = (sc4[tt][r] + wrow[tt * 16 + l15]) * SC;
        s = (kg <= q) ? s : -1e30f;
        float p = exp2f(s);
        pvv[tt][r] = p;
        l_r[r] += p;
      }
    }
    __builtin_amdgcn_wave_barrier();
    asm volatile("" ::: "memory");     // order W-reads before aliased P-writes

    // P -> LDS bf16, swizzled rows of 128B
#pragma unroll
    for (int tt = 0; tt < 4; tt++)
#pragma unroll
      for (int r = 0; r < 4; r++) {
        const int rowi = lg * 4 + r;
        const int cb = (32 * tt + 2 * l15) ^ ((rowi & 7) << 4);
        *(u16*)((char*)Pb + rowi * 128 + cb) = f2bf(pvv[tt][r]);
      }
    __builtin_amdgcn_wave_barrier();

    // PV from swizzled Plds (A) and Vlds (B)
#pragma unroll
    for (int s = 0; s < 2; s++) {
      const int acb = (s * 64 + lg * 16) ^ ((l15 & 7) << 4);
      bf16x8 aP = *reinterpret_cast<const bf16x8*>((const char*)Pb + l15 * 128 + acb);
#pragma unroll
      for (int dt = 0; dt < 4; dt++) {
        const int vrow = dt * 16 + l15;
        const int vcb = (s * 64 + lg * 16) ^ ((vrow & 7) << 4);
        bf16x8 bV = *reinterpret_cast<const bf16x8*>((const char*)Vlds + vrow * 128 + vcb);
        oacc[dt] = mfma16(aP, bV, oacc[dt]);
      }
    }
    __syncthreads();   // all waves done with K/V/P before restaging
  }

  // epilogue: one row-sum reduce, scale, store
#pragma unroll
  for (int r = 0; r < 4; r++) {
    float l = l_r[r];
#pragma unroll
    for (int xm = 1; xm < 16; xm <<= 1) l += __shfl_xor(l, xm);
    const float inv = 1.f / l;
    const int q = qw + lg * 4 + r;
#pragma unroll
    for (int dt = 0; dt < 4; dt++)
      Oout[(size_t)(b * 1024 + q) * 1024 + h * 64 + dt * 16 + l15] = f2bf(oacc[dt][r] * inv);
  }
}

// ---------------- launcher ----------------

extern "C" void kernel_launch(void* const* d_in, const int* in_sizes, int n_in,
                              void* d_out, int out_size, void* d_ws, size_t ws_size,
                              hipStream_t stream) {
  const float* x   = (const float*)d_in[0];
  const float* Wq  = (const float*)d_in[1];
  const float* bq  = (const float*)d_in[2];
  const float* Wk  = (const float*)d_in[3];
  const float* bk  = (const float*)d_in[4];
  const float* Wv  = (const float*)d_in[5];
  const float* bv  = (const float*)d_in[6];
  const float* Wo  = (const float*)d_in[7];
  const float* bo  = (const float*)d_in[8];
  const float* rel = (const float*)d_in[9];

  const size_t MB = 1024 * 1024;
  char* ws = (char*)d_ws;
  u16*   xb    = (u16*)(ws);                 // 8MB; reused for attn O after QKV GEMM
  u16*   Wt    = (u16*)(ws + 8 * MB);        // 4096x1024 bf16 (Wq^T|Wk^T|Wv^T|Wo^T)
  u16*   qkvb  = (u16*)(ws + 16 * MB);       // 4096x3072 bf16 (V region unused)
  u16*   vtb   = (u16*)(ws + 40 * MB);       // 4096x1024 bf16 (transposed V)
  u16*   relbb = (u16*)(ws + 48 * MB);       // 1024x64 bf16
  float* bqkv  = (float*)(ws + 49 * MB);     // 3072 f32
  u16*   Ob    = xb;

  // 1) all conversions/packs/transposes in ONE launch
  k_prep_all<<<8268, 256, 0, stream>>>(x, xb, Wq, Wk, Wv, Wo, Wt, rel, relbb, bq, bk, bv, bqkv);

  // 2) fused QKV projection (BK=64, BN=128); V block written transposed into vtb
  k_gemm<2, 128><<<dim3(24, 32), 256, 0, stream>>>(xb, Wt, bqkv, qkvb, vtb, 4096, 3072, 1024);

  // 3) attention: round-3 structure + hoisted rel loads
  k_attn<<<1024, 256, 0, stream>>>(qkvb, vtb, relbb, Ob);

  // 4) output projection (BK=64, BN=64 -> 512 blocks = 2/CU) -> fp32 d_out
  k_gemm<0, 64><<<dim3(16, 32), 256, 0, stream>>>(Ob, Wt + 3 * MB, bo, d_out, nullptr, 4096, 1024, 1024);
}

// Round 9
// 130.817 us; speedup vs baseline: 1.4758x; 1.0626x over previous
//
#include <hip/hip_runtime.h>

typedef unsigned short u16;
typedef __attribute__((ext_vector_type(8))) __bf16 bf16x8;
typedef __attribute__((ext_vector_type(4))) float f32x4;
typedef __attribute__((ext_vector_type(4))) u16 u16x4;

// ---------------- helpers ----------------

__device__ __forceinline__ u16 f2bf(float f) {
  unsigned u = __float_as_uint(f);
  u += 0x7fff + ((u >> 16) & 1);   // RNE
  return (u16)(u >> 16);
}

__device__ __forceinline__ f32x4 mfma16(bf16x8 a, bf16x8 b, f32x4 c) {
  return __builtin_amdgcn_mfma_f32_16x16x32_bf16(a, b, c, 0, 0, 0);
}

__device__ __forceinline__ void gload16(const void* g, void* l) {
  __builtin_amdgcn_global_load_lds(
      (__attribute__((address_space(1))) unsigned int*)(const_cast<void*>(g)),
      (__attribute__((address_space(3))) unsigned int*)l, 16, 0, 0);
}

// ---------------- fused prep kernel ----------------
// blocks [0,4096):     x f32 -> bf16 (1048576 float4 chunks)
// blocks [4096,8192):  W transpose+convert, z = (bx-4096)>>10, 32x32 tiles
// blocks [8192,8256):  rel f32 -> bf16
// blocks [8256,8268):  bias pack

__global__ void k_prep_all(const float* __restrict__ x, u16* __restrict__ xb,
                           const float* __restrict__ W0, const float* __restrict__ W1,
                           const float* __restrict__ W2, const float* __restrict__ W3,
                           u16* __restrict__ Wt,
                           const float* __restrict__ rel, u16* __restrict__ relb,
                           const float* __restrict__ bq, const float* __restrict__ bk,
                           const float* __restrict__ bv, float* __restrict__ bias) {
  __shared__ float tile[32][33];
  const int bx = blockIdx.x, t = threadIdx.x;
  if (bx < 4096) {
    int i = bx * 256 + t;
    float4 v = reinterpret_cast<const float4*>(x)[i];
    u16x4 o;
    o.x = f2bf(v.x); o.y = f2bf(v.y); o.z = f2bf(v.z); o.w = f2bf(v.w);
    reinterpret_cast<u16x4*>(xb)[i] = o;
  } else if (bx < 8192) {
    const int id = bx - 4096;
    const int z = id >> 10;
    const float* in = (z == 0) ? W0 : (z == 1) ? W1 : (z == 2) ? W2 : W3;
    u16* out = Wt + (size_t)z * 1024 * 1024;
    const int r0 = ((id >> 5) & 31) * 32, c0 = (id & 31) * 32;
    for (int i = t; i < 1024; i += 256) {
      int r = i >> 5, c = i & 31;
      tile[r][c] = in[(size_t)(r0 + r) * 1024 + c0 + c];
    }
    __syncthreads();
    for (int i = t; i < 1024; i += 256) {
      int r = i >> 5, c = i & 31;
      out[(size_t)(c0 + r) * 1024 + r0 + c] = f2bf(tile[c][r]);
    }
  } else if (bx < 8256) {
    int i = (bx - 8192) * 256 + t;
    float4 v = reinterpret_cast<const float4*>(rel)[i];
    u16x4 o;
    o.x = f2bf(v.x); o.y = f2bf(v.y); o.z = f2bf(v.z); o.w = f2bf(v.w);
    reinterpret_cast<u16x4*>(relb)[i] = o;
  } else {
    int i = (bx - 8256) * 256 + t;
    if (i < 3072) bias[i] = (i < 1024) ? bq[i] : (i < 2048 ? bk[i - 1024] : bv[i - 2048]);
  }
}

// ---------------- GEMM: C[m][n] = sum_k A[m][k]*B[n][k] + bias[n] ----------------
// BK=64, 2-barrier skeleton, 128xBN tile, XOR-16 swizzled LDS rows (staged via
// pre-swizzled global source + linear gload_lds dest; read back with same XOR).
// BN template: 128 (QKV, 768 blocks = 3/CU) or 64 (Wo, 512 blocks = 2/CU --
// doubles inter-block latency overlap for the latency-bound 1-block/CU case).
// MODE 0: fp32 output. MODE 2: bf16 output + cols >= 2048 (V block of the fused
// QKV GEMM) routed to Vaux transposed: Vaux[(b*1024 + (col-2048))*1024 + s].

template<int MODE, int BN>
__global__ __launch_bounds__(256) void k_gemm(
    const u16* __restrict__ A, const u16* __restrict__ B,
    const float* __restrict__ bias, void* __restrict__ Cout,
    u16* __restrict__ Vaux, int M, int N, int Kd)
{
  constexpr int NF = BN / 32;      // N fragments per wave (4 or 2)
  __shared__ u16 Alds[128 * 64];   // 16 KB, swizzled: byte = row*128 + (cb ^ ((row&7)<<4))
  __shared__ u16 Blds[BN * 64];
  const int t = threadIdx.x;
  const int lane = t & 63, wid = t >> 6;
  const int wr = wid >> 1, wc = wid & 1;
  const int l15 = lane & 15, lg = lane >> 4;
  const int m0 = blockIdx.y * 128, n0 = blockIdx.x * BN;

  const f32x4 fzero = {0.f, 0.f, 0.f, 0.f};
  f32x4 acc[4][NF];
#pragma unroll
  for (int i = 0; i < 4; i++)
#pragma unroll
    for (int j = 0; j < NF; j++) acc[i][j] = fzero;

  // staging: thread t stages A chunks {t+256*ci, ci<4}, B chunks {t+256*ci, ci<NF}.
  // chunk c: row = c>>3 (row&7 is ci-invariant), col byte = (c&7)*16, source col
  // inverse-swizzled so LDS holds the swizzled layout with a linear dest.
  const int srow = t >> 3;                                  // 0..31
  const int scb  = ((t & 7) * 16) ^ ((srow & 7) << 4);      // byte offset in 128B row
  const size_t abase = (size_t)(m0 + srow) * Kd + (scb >> 1);
  const size_t bbase = (size_t)(n0 + srow) * Kd + (scb >> 1);

  for (int k0 = 0; k0 < Kd; k0 += 64) {
#pragma unroll
    for (int ci = 0; ci < 4; ci++)
      gload16(A + abase + (size_t)(32 * ci) * Kd + k0, Alds + (t + 256 * ci) * 8);
#pragma unroll
    for (int ci = 0; ci < NF; ci++)
      gload16(B + bbase + (size_t)(32 * ci) * Kd + k0, Blds + (t + 256 * ci) * 8);
    __syncthreads();
#pragma unroll
    for (int kk = 0; kk < 2; kk++) {
      bf16x8 av[4], bv[NF];
#pragma unroll
      for (int mi = 0; mi < 4; mi++) {
        const int row = wr * 64 + mi * 16 + l15;
        av[mi] = *reinterpret_cast<const bf16x8*>(
            (const char*)Alds + row * 128 + ((kk * 64 + lg * 16) ^ ((row & 7) << 4)));
      }
#pragma unroll
      for (int ni = 0; ni < NF; ni++) {
        const int row = wc * (BN / 2) + ni * 16 + l15;
        bv[ni] = *reinterpret_cast<const bf16x8*>(
            (const char*)Blds + row * 128 + ((kk * 64 + lg * 16) ^ ((row & 7) << 4)));
      }
#pragma unroll
      for (int mi = 0; mi < 4; mi++)
#pragma unroll
        for (int ni = 0; ni < NF; ni++)
          acc[mi][ni] = mfma16(av[mi], bv[ni], acc[mi][ni]);
    }
    __syncthreads();
  }

#pragma unroll
  for (int mi = 0; mi < 4; mi++) {
#pragma unroll
    for (int ni = 0; ni < NF; ni++) {
      const int col = n0 + wc * (BN / 2) + ni * 16 + l15;
      const float bcol = bias[col];
#pragma unroll
      for (int r = 0; r < 4; r++) {
        const int row = m0 + wr * 64 + mi * 16 + lg * 4 + r;
        const float v = acc[mi][ni][r] + bcol;
        if (MODE == 0) {
          ((float*)Cout)[(size_t)row * N + col] = v;
        } else {
          if (col < 2048) {
            ((u16*)Cout)[(size_t)row * N + col] = f2bf(v);
          } else {
            const int bb = row >> 10, ss = row & 1023;
            Vaux[((size_t)bb * 1024 + (col - 2048)) * 1024 + ss] = f2bf(v);
          }
        }
      }
    }
  }
}

// ---------------- attention ----------------
// ROUND-3/7 VERSION RESTORED VERBATIM (64.0 us, reproduced 3x; VGPR 56,
// FETCH 12.85MB, conflicts 1.114M). The (rel-combine x load-placement) matrix
// is now fully measured:
//   inline + W-band LDS   : 64 us   <- THIS KERNEL (unique optimum)
//   inline + shuffle      : 101-109 us (bpermute chains serialize)
//   hoist  + W-band LDS   : 74 us  (r8: rel loads issued before the staging
//                                   burst miss L2 -> +4MB HBM, exposed latency)
//   hoist  + shuffle      : 101-118 us
// DO NOT restructure this kernel. Its stage->sync->compute single-buffered
// loop is a compiler-scheduling local optimum (5 structural variants all lost).

__global__ __launch_bounds__(256, 4) void k_attn(
    const u16* __restrict__ qkv,   // (4096, 3072): Q|K|V
    const u16* __restrict__ vt,    // (64*64, 1024): Vt[bh*64+d][s]
    const u16* __restrict__ relb,  // (1024, 64)
    u16* __restrict__ Oout)        // (4096, 1024)
{
  __shared__ u16 Klds[64 * 64];        // 8 KB, swizzled: byte = row*128 + (cb ^ ((row&7)<<4))
  __shared__ u16 Vlds[64 * 64];        // 8 KB, same swizzle (rows = d)
  __shared__ float Sbuf[4][16 * 84];   // 21 KB, per-wave: W band f32 (stride 84); P (bf16) aliases base

  const int t = threadIdx.x;
  const int lane = t & 63, w = t >> 6;
  const int l15 = lane & 15, lg = lane >> 4;
  const int blk = blockIdx.x;
  const int bh = blk & 63;             // blocks of a bh share an XCD (blk%8 == bh%8)
  // balanced q-tile mapping: groups {g, g+4, g+8, g+12} co-reside on one CU;
  // qbt per quarter j: {15-r, 8+r, 7-r, r} -> per-CU sum(nk) == 34 for all r.
  const int g = blk >> 6;
  const int jq = g >> 2, rq = g & 3;
  const int qbt = (jq == 0) ? (15 - rq) : (jq == 1) ? (8 + rq) : (jq == 2) ? (7 - rq) : rq;
  const int b = bh >> 4, h = bh & 15;
  const int qb = qbt * 64;
  const int qw = qb + w * 16;

  float* Wb = Sbuf[w];
  u16* Pb = (u16*)Sbuf[w];             // aliases Wb; ordering via wave_barrier fences

  const f32x4 fzero = {0.f, 0.f, 0.f, 0.f};

  // Q A-fragments, held in registers
  const size_t qrow = (size_t)(b * 1024 + qw + l15) * 3072 + h * 64;
  bf16x8 aQ0 = *reinterpret_cast<const bf16x8*>(qkv + qrow + lg * 8);
  bf16x8 aQ1 = *reinterpret_cast<const bf16x8*>(qkv + qrow + 32 + lg * 8);

  f32x4 oacc[4];
  float l_r[4];
#pragma unroll
  for (int r = 0; r < 4; r++) { oacc[r] = fzero; l_r[r] = 0.f; }

  // staging: thread t stages chunks t and t+256 (16B each) for K and V.
  // dest byte t*16 -> logical (row = t>>3, cb = (t&7)*16); source col byte is
  // inverse-swizzled so LDS holds the swizzled layout with a linear dest.
  const int srow = t >> 3;
  const int scb = ((t & 7) * 16) ^ ((srow & 7) << 4);
  const u16* Ks0 = qkv + (size_t)(b * 1024 + srow) * 3072 + 1024 + h * 64 + (scb >> 1);
  const u16* Ks1 = Ks0 + 32 * 3072;
  const u16* Vs0 = vt + (size_t)(bh * 64 + srow) * 1024 + (scb >> 1);
  const u16* Vs1 = Vs0 + 32 * 1024;
  u16* Kd0 = Klds + t * 8;  u16* Kd1 = Klds + (t + 256) * 8;
  u16* Vd0 = Vlds + t * 8;  u16* Vd1 = Vlds + (t + 256) * 8;

  const int nk = qbt + 1;              // uniform trip count across the 4 waves
  const float SC = 0.125f * 1.44269504f;   // fold 1/sqrt(D) and log2(e)

  for (int kt = 0; kt < nk; kt++) {
    const int k0 = kt * 64;
    gload16(Ks0 + (size_t)k0 * 3072, Kd0);
    gload16(Ks1 + (size_t)k0 * 3072, Kd1);
    gload16(Vs0 + k0, Vd0);
    gload16(Vs1 + k0, Vd1);
    __syncthreads();   // drains vmcnt for all waves; K/V tile ready

    // content scores: 16 q x 64 k from swizzled Klds
    f32x4 sc4[4];
#pragma unroll
    for (int tt = 0; tt < 4; tt++) sc4[tt] = fzero;
#pragma unroll
    for (int tt = 0; tt < 4; tt++) {
      const int row = tt * 16 + l15;
      const int sw = (row & 7) << 4;
      bf16x8 b0 = *reinterpret_cast<const bf16x8*>((const char*)Klds + row * 128 + ((lg * 16) ^ sw));
      bf16x8 b1 = *reinterpret_cast<const bf16x8*>((const char*)Klds + row * 128 + ((64 + lg * 16) ^ sw));
      sc4[tt] = mfma16(aQ0, b0, sc4[tt]);
      sc4[tt] = mfma16(aQ1, b1, sc4[tt]);
    }

    // rel band: W[q][j] = Q[q]·rel[rbase+j], j in [0,80); direct global (L2-hot)
    const int rbase = 1008 + k0 - qw;
#pragma unroll
    for (int wj = 0; wj < 5; wj++) {
      int rr = rbase + wj * 16 + l15;
      rr = rr < 0 ? 0 : (rr > 1023 ? 1023 : rr);   // clamped rows feed only masked entries
      const u16* rp = relb + rr * 64;
      bf16x8 b0 = *reinterpret_cast<const bf16x8*>(rp + lg * 8);
      bf16x8 b1 = *reinterpret_cast<const bf16x8*>(rp + 32 + lg * 8);
      f32x4 z = fzero;
      z = mfma16(aQ0, b0, z);
      z = mfma16(aQ1, b1, z);
#pragma unroll
      for (int r = 0; r < 4; r++)
        Wb[(lg * 4 + r) * 84 + wj * 16 + l15] = z[r];
    }
    __builtin_amdgcn_wave_barrier();

    // combine + mask + exp2 (defer-max: static max 0); per-lane l partials
    float pvv[4][4];
#pragma unroll
    for (int r = 0; r < 4; r++) {
      const int rowi = lg * 4 + r;
      const int q = qw + rowi;
      const float* wrow = Wb + rowi * 84 + (15 - rowi);
#pragma unroll
      for (int tt = 0; tt < 4; tt++) {
        const int kg = k0 + tt * 16 + l15;
        float s = (sc4[tt][r] + wrow[tt * 16 + l15]) * SC;
        s = (kg <= q) ? s : -1e30f;
        float p = exp2f(s);
        pvv[tt][r] = p;
        l_r[r] += p;
      }
    }
    __builtin_amdgcn_wave_barrier();
    asm volatile("" ::: "memory");     // order W-reads before aliased P-writes

    // P -> LDS bf16, swizzled rows of 128B
#pragma unroll
    for (int tt = 0; tt < 4; tt++)
#pragma unroll
      for (int r = 0; r < 4; r++) {
        const int rowi = lg * 4 + r;
        const int cb = (32 * tt + 2 * l15) ^ ((rowi & 7) << 4);
        *(u16*)((char*)Pb + rowi * 128 + cb) = f2bf(pvv[tt][r]);
      }
    __builtin_amdgcn_wave_barrier();

    // PV from swizzled Plds (A) and Vlds (B)
#pragma unroll
    for (int s = 0; s < 2; s++) {
      const int acb = (s * 64 + lg * 16) ^ ((l15 & 7) << 4);
      bf16x8 aP = *reinterpret_cast<const bf16x8*>((const char*)Pb + l15 * 128 + acb);
#pragma unroll
      for (int dt = 0; dt < 4; dt++) {
        const int vrow = dt * 16 + l15;
        const int vcb = (s * 64 + lg * 16) ^ ((vrow & 7) << 4);
        bf16x8 bV = *reinterpret_cast<const bf16x8*>((const char*)Vlds + vrow * 128 + vcb);
        oacc[dt] = mfma16(aP, bV, oacc[dt]);
      }
    }
    __syncthreads();   // all waves done with K/V/P before restaging
  }

  // epilogue: one row-sum reduce, scale, store
#pragma unroll
  for (int r = 0; r < 4; r++) {
    float l = l_r[r];
#pragma unroll
    for (int xm = 1; xm < 16; xm <<= 1) l += __shfl_xor(l, xm);
    const float inv = 1.f / l;
    const int q = qw + lg * 4 + r;
#pragma unroll
    for (int dt = 0; dt < 4; dt++)
      Oout[(size_t)(b * 1024 + q) * 1024 + h * 64 + dt * 16 + l15] = f2bf(oacc[dt][r] * inv);
  }
}

// ---------------- launcher ----------------

extern "C" void kernel_launch(void* const* d_in, const int* in_sizes, int n_in,
                              void* d_out, int out_size, void* d_ws, size_t ws_size,
                              hipStream_t stream) {
  const float* x   = (const float*)d_in[0];
  const float* Wq  = (const float*)d_in[1];
  const float* bq  = (const float*)d_in[2];
  const float* Wk  = (const float*)d_in[3];
  const float* bk  = (const float*)d_in[4];
  const float* Wv  = (const float*)d_in[5];
  const float* bv  = (const float*)d_in[6];
  const float* Wo  = (const float*)d_in[7];
  const float* bo  = (const float*)d_in[8];
  const float* rel = (const float*)d_in[9];

  const size_t MB = 1024 * 1024;
  char* ws = (char*)d_ws;
  u16*   xb    = (u16*)(ws);                 // 8MB; reused for attn O after QKV GEMM
  u16*   Wt    = (u16*)(ws + 8 * MB);        // 4096x1024 bf16 (Wq^T|Wk^T|Wv^T|Wo^T)
  u16*   qkvb  = (u16*)(ws + 16 * MB);       // 4096x3072 bf16 (V region unused)
  u16*   vtb   = (u16*)(ws + 40 * MB);       // 4096x1024 bf16 (transposed V)
  u16*   relbb = (u16*)(ws + 48 * MB);       // 1024x64 bf16
  float* bqkv  = (float*)(ws + 49 * MB);     // 3072 f32
  u16*   Ob    = xb;

  // 1) all conversions/packs/transposes in ONE launch
  k_prep_all<<<8268, 256, 0, stream>>>(x, xb, Wq, Wk, Wv, Wo, Wt, rel, relbb, bq, bk, bv, bqkv);

  // 2) fused QKV projection (BK=64, BN=128); V block written transposed into vtb
  k_gemm<2, 128><<<dim3(24, 32), 256, 0, stream>>>(xb, Wt, bqkv, qkvb, vtb, 4096, 3072, 1024);

  // 3) attention: round-3/7 proven kernel (64.0 us)
  k_attn<<<1024, 256, 0, stream>>>(qkvb, vtb, relbb, Ob);

  // 4) output projection (BK=64, BN=64 -> 512 blocks = 2/CU) -> fp32 d_out
  k_gemm<0, 64><<<dim3(16, 32), 256, 0, stream>>>(Ob, Wt + 3 * MB, bo, d_out, nullptr, 4096, 1024, 1024);
}